// Round 2
// baseline (223.792 us; speedup 1.0000x reference)
//
#include <hip/hip_runtime.h>
#include <hip/hip_bf16.h>

// Pipeline (R9): wtrans -> fused(gemm||fill2) -> bucket_gather
//  - R8 post-mortem: 8-deep gather pipeline HURT (VGPR 40 -> compiler
//    recycled regs, early waitcnts; 66->75us). Reverted to 4-deep/(256,8).
//  - R9: BNODES 64->32 (3125 blocks, 12.2/CU avg) to raise gather occupancy
//    (was 50%, grid-quantization + tail). Tests parallelism-bound vs
//    L3-BW-bound: if hbm_gbps stays ~3.5TB/s we're at the L3 ceiling.
//  - NFILL 256->64: 8 edges per (block,bucket) -> 64B contiguous epk
//    sub-windows -> scatter writes coalesce into cache lines.

#define D 128
#define NB_SHIFT 5
#define BNODES 32
#define MAXB 3200            // >= nb = 3125
#define CAPB 800             // mean 512 + 12.7 sigma
#define RPT 4                // ceil(CAPB/256)
#define XSTR 136             // LDS row stride (ushorts): 272B = 4-bank shift/row
#define NFILL 64             // fill2 blocks in fused kernel

using bf16x8 = __attribute__((ext_vector_type(8))) short;
using f32x4  = __attribute__((ext_vector_type(4))) float;

__device__ inline unsigned short f2bf(float f) {
    unsigned u = __float_as_uint(f);
    u += 0x7fffu + ((u >> 16) & 1u);
    return (unsigned short)(u >> 16);
}
__device__ inline float bflo(unsigned w) { return __uint_as_float(w << 16); }
__device__ inline float bfhi(unsigned w) { return __uint_as_float(w & 0xffff0000u); }

// ---------------- wtrans: WT[n][k] = bf16(W[k][n]); also zeroes cursor ----------------
__global__ __launch_bounds__(256) void wtrans(const float* __restrict__ W,
                                              unsigned short* __restrict__ WT,
                                              int* cursor, int nb) {
    const int t = threadIdx.x, b = blockIdx.x;   // 8 blocks
    const int n  = (b << 4) | (t & 15);
    const int k0 = (t >> 4) << 3;
#pragma unroll
    for (int k = k0; k < k0 + 8; ++k)
        WT[n * D + k] = f2bf(W[k * D + n]);
    if (b == 0)
        for (int i = t; i < nb; i += 256) cursor[i] = 0;
}

// ---------------- fused kernel: fill2 path + gemm path ----------------
// LDS union: gemm needs Xl(17.4KB)+Wl(34.8KB)=52.2KB; fill2 needs 25.6KB.
#define SMEM_BYTES (64 * XSTR * 2 + 128 * XSTR * 2)

__device__ void gemm_path(const float* __restrict__ X,
                          const unsigned short* __restrict__ WT,
                          unsigned short* __restrict__ S,
                          int nRows, int blk, char* smem) {
    unsigned short* Xl = (unsigned short*)smem;                    // [64][XSTR]
    unsigned short* Wl = (unsigned short*)(smem + 64 * XSTR * 2);  // [128][XSTR]

    const int t = threadIdx.x;                 // 0..1023
    const int row0 = blk * 64;

    // stage WT (16384 ushort = 2048 uint4), coalesced, 2 iters
    const uint4* WT4 = (const uint4*)WT;
    uint4* Wl4 = (uint4*)Wl;
#pragma unroll
    for (int i = t; i < 2048; i += 1024) {
        int n = i >> 4, kc8 = i & 15;
        Wl4[n * (XSTR / 8) + kc8] = WT4[i];
    }

    // stage X tile fp32 -> bf16 (2048 float4), 2 iters
    const float4* X4 = (const float4*)X;
    ushort4* Xl4 = (ushort4*)Xl;
#pragma unroll
    for (int i = t; i < 2048; i += 1024) {
        int r = i >> 5, c = i & 31;
        int gr = row0 + r;
        float4 v = make_float4(0.f, 0.f, 0.f, 0.f);
        if (gr < nRows) v = X4[(size_t)gr * 32 + c];
        ushort4 p;
        p.x = f2bf(v.x); p.y = f2bf(v.y); p.z = f2bf(v.z); p.w = f2bf(v.w);
        Xl4[r * (XSTR / 4) + c] = p;
    }
    __syncthreads();

    // 16 waves: wave w -> rows (w&3)*16..+15, nt pair (w>>2)*2..+1
    const int wv = t >> 6, lane = t & 63;
    const int m = lane & 15, quad = lane >> 4;
    const int m0  = (wv & 3) << 4;
    const int nt0 = (wv >> 2) << 1;

    f32x4 acc0 = {0.f, 0.f, 0.f, 0.f};
    f32x4 acc1 = {0.f, 0.f, 0.f, 0.f};

#pragma unroll
    for (int kc = 0; kc < 4; ++kc) {
        bf16x8 a = *(const bf16x8*)(Xl + (m0 + m) * XSTR + kc * 32 + quad * 8);
        bf16x8 b0 = *(const bf16x8*)(Wl + ((nt0 + 0) * 16 + m) * XSTR + kc * 32 + quad * 8);
        bf16x8 b1 = *(const bf16x8*)(Wl + ((nt0 + 1) * 16 + m) * XSTR + kc * 32 + quad * 8);
        acc0 = __builtin_amdgcn_mfma_f32_16x16x32_bf16(a, b0, acc0, 0, 0, 0);
        acc1 = __builtin_amdgcn_mfma_f32_16x16x32_bf16(a, b1, acc1, 0, 0, 0);
    }

    // D[row = quad*4+r][col = nt*16+m]
#pragma unroll
    for (int r = 0; r < 4; ++r) {
        int gr = row0 + m0 + quad * 4 + r;
        if (gr < nRows) {
            S[(size_t)gr * D + (nt0 + 0) * 16 + m] = f2bf(acc0[r]);
            S[(size_t)gr * D + (nt0 + 1) * 16 + m] = f2bf(acc1[r]);
        }
    }
}

__device__ void fill2_path(const int* __restrict__ src,
                           const int* __restrict__ dst,
                           const float* __restrict__ vals,
                           int* gcursor, int2* __restrict__ epk,
                           int E, int nb, int blk, char* smem) {
    int* h   = (int*)smem;                  // [MAXB]
    int* cur = (int*)(smem + MAXB * 4);     // [MAXB]
    const int t = threadIdx.x;              // 0..1023
    for (int i = t; i < nb; i += 1024) h[i] = 0;
    __syncthreads();

    int chunk = (E + NFILL - 1) / NFILL;
    chunk = (chunk + 3) & ~3;                     // keep int4 alignment
    const int s0 = min(E, blk * chunk);
    const int s1 = min(E, s0 + chunk);
    const int vend = s0 + ((s1 - s0) & ~3);       // int4 region

    // pass 1: histogram, int4 loads (4 edges/thread/iter)
    int e = s0 + (t << 2);
    for (; e + 4 <= vend; e += 4096) {
        int4 d = *(const int4*)(dst + e);
        atomicAdd(&h[d.x >> NB_SHIFT], 1);
        atomicAdd(&h[d.y >> NB_SHIFT], 1);
        atomicAdd(&h[d.z >> NB_SHIFT], 1);
        atomicAdd(&h[d.w >> NB_SHIFT], 1);
    }
    for (e = vend + t; e < s1; e += 1024) atomicAdd(&h[dst[e] >> NB_SHIFT], 1);
    __syncthreads();

    // reserve per-WG sub-window inside each bucket's fixed window
    for (int i = t; i < nb; i += 1024) {
        int c = h[i];
        cur[i] = c ? (i * CAPB + atomicAdd(&gcursor[i], c)) : 0;
    }
    __syncthreads();

    // pass 2: scatter (~8 edges per (block,bucket) -> 64B sub-windows)
    e = s0 + (t << 2);
    for (; e + 4 <= vend; e += 4096) {
        int4   d = *(const int4*)(dst + e);
        int4   s = *(const int4*)(src + e);
        float4 v = *(const float4*)(vals + e);
        int p0 = atomicAdd(&cur[d.x >> NB_SHIFT], 1);
        int p1 = atomicAdd(&cur[d.y >> NB_SHIFT], 1);
        int p2 = atomicAdd(&cur[d.z >> NB_SHIFT], 1);
        int p3 = atomicAdd(&cur[d.w >> NB_SHIFT], 1);
        epk[p0] = make_int2(s.x | ((d.x & (BNODES - 1)) << 20), __float_as_int(v.x));
        epk[p1] = make_int2(s.y | ((d.y & (BNODES - 1)) << 20), __float_as_int(v.y));
        epk[p2] = make_int2(s.z | ((d.z & (BNODES - 1)) << 20), __float_as_int(v.z));
        epk[p3] = make_int2(s.w | ((d.w & (BNODES - 1)) << 20), __float_as_int(v.w));
    }
    for (e = vend + t; e < s1; e += 1024) {
        int d = dst[e];
        int pos = atomicAdd(&cur[d >> NB_SHIFT], 1);
        epk[pos] = make_int2(src[e] | ((d & (BNODES - 1)) << 20), __float_as_int(vals[e]));
    }
}

__global__ __launch_bounds__(1024, 8) void fused_pre(const float* __restrict__ X,
                                                     const unsigned short* __restrict__ WT,
                                                     unsigned short* __restrict__ S,
                                                     int nRows,
                                                     const int* __restrict__ src,
                                                     const int* __restrict__ dst,
                                                     const float* __restrict__ vals,
                                                     int* gcursor, int2* __restrict__ epk,
                                                     int E, int nb) {
    __shared__ char smem[SMEM_BYTES];
    const int bid = blockIdx.x;
    if (bid < NFILL)
        fill2_path(src, dst, vals, gcursor, epk, E, nb, bid, smem);
    else
        gemm_path(X, WT, S, nRows, bid - NFILL, smem);
}

// ---------------- bucket_gather: reg-staged sort + per-node reg accum ----------------
// 3125 blocks of 256 thr; ~6.8 KB LDS; 4-deep gather pipeline (known-good).
#define ACC8(e, mm) { float v = __int_as_float(e.y);                         \
    a[0] = fmaf(v, bflo(mm.x), a[0]); a[1] = fmaf(v, bfhi(mm.x), a[1]);      \
    a[2] = fmaf(v, bflo(mm.y), a[2]); a[3] = fmaf(v, bfhi(mm.y), a[3]);      \
    a[4] = fmaf(v, bflo(mm.z), a[4]); a[5] = fmaf(v, bfhi(mm.z), a[5]);      \
    a[6] = fmaf(v, bflo(mm.w), a[6]); a[7] = fmaf(v, bfhi(mm.w), a[7]); }

__global__ __launch_bounds__(256, 8) void bucket_gather(const unsigned short* __restrict__ support,
                                                        const int* __restrict__ gcursor,
                                                        const int2* __restrict__ epk,
                                                        float* __restrict__ out, int N) {
    __shared__ int2 se[CAPB];       // 6.4 KB
    __shared__ int  hist[BNODES];
    __shared__ int  rows[BNODES];
    __shared__ int  cur[BNODES];

    const int t   = threadIdx.x;
    const int b   = blockIdx.x;
    const int cnt = min(gcursor[b], CAPB);
    const int beg = b * CAPB;

    if (t < BNODES) hist[t] = 0;
    __syncthreads();

    // stage this thread's edges in registers: ONE global epk read total
    int2 r[RPT];
#pragma unroll
    for (int i = 0; i < RPT; ++i) {
        int idx = t + (i << 8);
        if (idx < cnt) r[i] = epk[beg + idx];
    }
#pragma unroll
    for (int i = 0; i < RPT; ++i) {
        int idx = t + (i << 8);
        if (idx < cnt) atomicAdd(&hist[(r[i].x >> 20) & (BNODES - 1)], 1);
    }
    __syncthreads();

    // Hillis-Steele inclusive scan of BNODES counters
    if (t < BNODES) rows[t] = hist[t];
    __syncthreads();
#pragma unroll
    for (int off = 1; off < BNODES; off <<= 1) {
        int v = 0;
        if (t < BNODES && t >= off) v = rows[t - off];
        __syncthreads();
        if (t < BNODES && t >= off) rows[t] += v;
        __syncthreads();
    }
    if (t < BNODES) cur[t] = rows[t] - hist[t];
    __syncthreads();

    // scatter registers into sorted LDS order
#pragma unroll
    for (int i = 0; i < RPT; ++i) {
        int idx = t + (i << 8);
        if (idx < cnt) {
            int pos = atomicAdd(&cur[(r[i].x >> 20) & (BNODES - 1)], 1);
            se[pos] = r[i];
        }
    }
    __syncthreads();

    // per-node accumulation: group g (16 lanes) handles nodes g, g+16
    const int g = t >> 4, lane = t & 15;
    const int node0 = b << NB_SHIFT;
    const uint4* S4 = (const uint4*)support;
    float4* o4 = (float4*)out;

#pragma unroll
    for (int nn = g; nn < BNODES; nn += 16) {
        const int send = rows[nn];
        const int sbeg = send - hist[nn];

        float a[8];
#pragma unroll
        for (int k = 0; k < 8; ++k) a[k] = 0.f;

        int j = sbeg;
        for (; j + 4 <= send; j += 4) {          // 4 outstanding 256 B gathers
            int2 e0 = se[j], e1 = se[j + 1], e2 = se[j + 2], e3 = se[j + 3];
            uint4 m0 = S4[(size_t)(e0.x & 0xFFFFF) * 16 + lane];
            uint4 m1 = S4[(size_t)(e1.x & 0xFFFFF) * 16 + lane];
            uint4 m2 = S4[(size_t)(e2.x & 0xFFFFF) * 16 + lane];
            uint4 m3 = S4[(size_t)(e3.x & 0xFFFFF) * 16 + lane];
            ACC8(e0, m0); ACC8(e1, m1); ACC8(e2, m2); ACC8(e3, m3);
        }
        for (; j < send; ++j) {
            int2 e0 = se[j];
            uint4 m0 = S4[(size_t)(e0.x & 0xFFFFF) * 16 + lane];
            ACC8(e0, m0);
        }

        const int gn = node0 + nn;
        if (gn < N) {
            size_t base = (size_t)gn * 32 + 2 * lane;
            float4 lo = make_float4(fmaxf(a[0], 0.f), fmaxf(a[1], 0.f),
                                    fmaxf(a[2], 0.f), fmaxf(a[3], 0.f));
            float4 hi = make_float4(fmaxf(a[4], 0.f), fmaxf(a[5], 0.f),
                                    fmaxf(a[6], 0.f), fmaxf(a[7], 0.f));
            o4[base]     = lo;
            o4[base + 1] = hi;
        }
    }
}

extern "C" void kernel_launch(void* const* d_in, const int* in_sizes, int n_in,
                              void* d_out, int out_size, void* d_ws, size_t ws_size,
                              hipStream_t stream) {
    const float* X    = (const float*)d_in[0];
    const float* W    = (const float*)d_in[1];
    const float* vals = (const float*)d_in[2];
    const int*   src  = (const int*)d_in[3];
    const int*   dst  = (const int*)d_in[4];
    float*       out  = (float*)d_out;

    const int N  = in_sizes[0] / D;
    const int E  = in_sizes[2];
    const int nb = (N + BNODES - 1) / BNODES;   // 3125

    size_t off = 0;
    auto take = [&](size_t bytes) {
        size_t p = off;
        off = (off + bytes + 255) & ~(size_t)255;
        return p;
    };
    char* ws = (char*)d_ws;
    size_t o_support = take((size_t)N * D * sizeof(unsigned short));
    size_t o_wt      = take((size_t)D * D * sizeof(unsigned short));
    size_t o_cursor  = take((size_t)nb * sizeof(int));
    size_t o_epk     = take(((size_t)nb * CAPB + 1024) * sizeof(int2));
    (void)ws_size;

    unsigned short* support = (unsigned short*)(ws + o_support);
    unsigned short* WT      = (unsigned short*)(ws + o_wt);
    int*  cursor = (int*)(ws + o_cursor);
    int2* epk    = (int2*)(ws + o_epk);

    // 1) WT = bf16(W^T); zero bucket cursors
    wtrans<<<8, 256, 0, stream>>>(W, WT, cursor, nb);

    // 2) fused: fill2 (blocks 0..63) || gemm (blocks 64..64+nbG-1)
    const int nbG = (N + 63) / 64;
    fused_pre<<<NFILL + nbG, 1024, 0, stream>>>(X, WT, support, N,
                                                src, dst, vals, cursor, epk, E, nb);

    // 3) per-bucket sort + gather + ReLU
    bucket_gather<<<nb, 256, 0, stream>>>(support, cursor, epk, out, N);
}

// Round 3
// 213.447 us; speedup vs baseline: 1.0485x; 1.0485x over previous
//
#include <hip/hip_runtime.h>
#include <hip/hip_bf16.h>

// Pipeline (R10): memset(cursor) -> fused(gemm||fill2) -> bucket_gather
//  - R9 post-mortem: NFILL=64 serialized fill (64 blocks on 256 CUs, all
//    counters low = latency signature); BNODES=32 no win. Reverted both.
//  - bucket_gather = exact R0 version (66.5us known-good: BNODES=64,
//    4-deep gather, VGPR 32, bounds(256,8)).
//  - fused_pre = R1 config (NFILL=256: 1 fill block/CU) PLUS in-block W
//    transpose (fp32 W -> bf16 Wl in LDS), eliminating the wtrans kernel
//    and the WT global round-trip. Cursor zeroing via hipMemsetAsync.

#define D 128
#define NB_SHIFT 6
#define BNODES 64
#define MAXB 2048            // >= nb = 1563
#define CAPB 1408            // mean 1023 + 12 sigma
#define RPT 6                // ceil(CAPB/256)
#define XSTR 136             // LDS row stride (ushorts): 272B = 4-bank shift/row
#define NFILL 256            // fill2 blocks in fused kernel (1 per CU)

using bf16x8 = __attribute__((ext_vector_type(8))) short;
using f32x4  = __attribute__((ext_vector_type(4))) float;

__device__ inline unsigned short f2bf(float f) {
    unsigned u = __float_as_uint(f);
    u += 0x7fffu + ((u >> 16) & 1u);
    return (unsigned short)(u >> 16);
}
__device__ inline float bflo(unsigned w) { return __uint_as_float(w << 16); }
__device__ inline float bfhi(unsigned w) { return __uint_as_float(w & 0xffff0000u); }

// ---------------- fused kernel: fill2 path + gemm path ----------------
// LDS union: gemm needs Xl(17.4KB)+Wl(34.8KB)=52.2KB; fill2 needs 16KB.
#define SMEM_BYTES (64 * XSTR * 2 + 128 * XSTR * 2)

__device__ void gemm_path(const float* __restrict__ X,
                          const float* __restrict__ W,
                          unsigned short* __restrict__ S,
                          int nRows, int blk, char* smem) {
    unsigned short* Xl = (unsigned short*)smem;                    // [64][XSTR]
    unsigned short* Wl = (unsigned short*)(smem + 64 * XSTR * 2);  // [128][XSTR]

    const int t = threadIdx.x;                 // 0..1023
    const int row0 = blk * 64;

    // stage W fp32 [k][n] -> bf16 Wl[n][k] (transpose), 4096 float4 reads.
    // W is 64KB, L2-resident after first touch per XCD.
    const float4* W4 = (const float4*)W;
#pragma unroll
    for (int i = t; i < 4096; i += 1024) {
        int k  = i >> 5;           // 0..127
        int n4 = (i & 31) << 2;    // 0,4,...,124
        float4 v = W4[i];
        Wl[(n4 + 0) * XSTR + k] = f2bf(v.x);
        Wl[(n4 + 1) * XSTR + k] = f2bf(v.y);
        Wl[(n4 + 2) * XSTR + k] = f2bf(v.z);
        Wl[(n4 + 3) * XSTR + k] = f2bf(v.w);
    }

    // stage X tile fp32 -> bf16 (2048 float4), 2 iters
    const float4* X4 = (const float4*)X;
    ushort4* Xl4 = (ushort4*)Xl;
#pragma unroll
    for (int i = t; i < 2048; i += 1024) {
        int r = i >> 5, c = i & 31;
        int gr = row0 + r;
        float4 v = make_float4(0.f, 0.f, 0.f, 0.f);
        if (gr < nRows) v = X4[(size_t)gr * 32 + c];
        ushort4 p;
        p.x = f2bf(v.x); p.y = f2bf(v.y); p.z = f2bf(v.z); p.w = f2bf(v.w);
        Xl4[r * (XSTR / 4) + c] = p;
    }
    __syncthreads();

    // 16 waves: wave w -> rows (w&3)*16..+15, nt pair (w>>2)*2..+1
    const int wv = t >> 6, lane = t & 63;
    const int m = lane & 15, quad = lane >> 4;
    const int m0  = (wv & 3) << 4;
    const int nt0 = (wv >> 2) << 1;

    f32x4 acc0 = {0.f, 0.f, 0.f, 0.f};
    f32x4 acc1 = {0.f, 0.f, 0.f, 0.f};

#pragma unroll
    for (int kc = 0; kc < 4; ++kc) {
        bf16x8 a = *(const bf16x8*)(Xl + (m0 + m) * XSTR + kc * 32 + quad * 8);
        bf16x8 b0 = *(const bf16x8*)(Wl + ((nt0 + 0) * 16 + m) * XSTR + kc * 32 + quad * 8);
        bf16x8 b1 = *(const bf16x8*)(Wl + ((nt0 + 1) * 16 + m) * XSTR + kc * 32 + quad * 8);
        acc0 = __builtin_amdgcn_mfma_f32_16x16x32_bf16(a, b0, acc0, 0, 0, 0);
        acc1 = __builtin_amdgcn_mfma_f32_16x16x32_bf16(a, b1, acc1, 0, 0, 0);
    }

    // D[row = quad*4+r][col = nt*16+m]
#pragma unroll
    for (int r = 0; r < 4; ++r) {
        int gr = row0 + m0 + quad * 4 + r;
        if (gr < nRows) {
            S[(size_t)gr * D + (nt0 + 0) * 16 + m] = f2bf(acc0[r]);
            S[(size_t)gr * D + (nt0 + 1) * 16 + m] = f2bf(acc1[r]);
        }
    }
}

__device__ void fill2_path(const int* __restrict__ src,
                           const int* __restrict__ dst,
                           const float* __restrict__ vals,
                           int* gcursor, int2* __restrict__ epk,
                           int E, int nb, int blk, char* smem) {
    int* h   = (int*)smem;                  // [MAXB]
    int* cur = (int*)(smem + MAXB * 4);     // [MAXB]
    const int t = threadIdx.x;              // 0..1023
    for (int i = t; i < nb; i += 1024) h[i] = 0;
    __syncthreads();

    int chunk = (E + NFILL - 1) / NFILL;
    chunk = (chunk + 3) & ~3;                     // keep int4 alignment
    const int s0 = min(E, blk * chunk);
    const int s1 = min(E, s0 + chunk);
    const int vend = s0 + ((s1 - s0) & ~3);       // int4 region

    // pass 1: histogram, int4 loads (4 edges/thread/iter)
    int e = s0 + (t << 2);
    for (; e + 4 <= vend; e += 4096) {
        int4 d = *(const int4*)(dst + e);
        atomicAdd(&h[d.x >> NB_SHIFT], 1);
        atomicAdd(&h[d.y >> NB_SHIFT], 1);
        atomicAdd(&h[d.z >> NB_SHIFT], 1);
        atomicAdd(&h[d.w >> NB_SHIFT], 1);
    }
    for (e = vend + t; e < s1; e += 1024) atomicAdd(&h[dst[e] >> NB_SHIFT], 1);
    __syncthreads();

    // reserve per-WG sub-window inside each bucket's fixed window
    for (int i = t; i < nb; i += 1024) {
        int c = h[i];
        cur[i] = c ? (i * CAPB + atomicAdd(&gcursor[i], c)) : 0;
    }
    __syncthreads();

    // pass 2: scatter
    e = s0 + (t << 2);
    for (; e + 4 <= vend; e += 4096) {
        int4   d = *(const int4*)(dst + e);
        int4   s = *(const int4*)(src + e);
        float4 v = *(const float4*)(vals + e);
        int p0 = atomicAdd(&cur[d.x >> NB_SHIFT], 1);
        int p1 = atomicAdd(&cur[d.y >> NB_SHIFT], 1);
        int p2 = atomicAdd(&cur[d.z >> NB_SHIFT], 1);
        int p3 = atomicAdd(&cur[d.w >> NB_SHIFT], 1);
        epk[p0] = make_int2(s.x | ((d.x & (BNODES - 1)) << 20), __float_as_int(v.x));
        epk[p1] = make_int2(s.y | ((d.y & (BNODES - 1)) << 20), __float_as_int(v.y));
        epk[p2] = make_int2(s.z | ((d.z & (BNODES - 1)) << 20), __float_as_int(v.z));
        epk[p3] = make_int2(s.w | ((d.w & (BNODES - 1)) << 20), __float_as_int(v.w));
    }
    for (e = vend + t; e < s1; e += 1024) {
        int d = dst[e];
        int pos = atomicAdd(&cur[d >> NB_SHIFT], 1);
        epk[pos] = make_int2(src[e] | ((d & (BNODES - 1)) << 20), __float_as_int(vals[e]));
    }
}

__global__ __launch_bounds__(1024, 8) void fused_pre(const float* __restrict__ X,
                                                     const float* __restrict__ W,
                                                     unsigned short* __restrict__ S,
                                                     int nRows,
                                                     const int* __restrict__ src,
                                                     const int* __restrict__ dst,
                                                     const float* __restrict__ vals,
                                                     int* gcursor, int2* __restrict__ epk,
                                                     int E, int nb) {
    __shared__ char smem[SMEM_BYTES];
    const int bid = blockIdx.x;
    if (bid < NFILL)
        fill2_path(src, dst, vals, gcursor, epk, E, nb, bid, smem);
    else
        gemm_path(X, W, S, nRows, bid - NFILL, smem);
}

// ---------------- bucket_gather: reg-staged sort + per-node reg accum ----------------
// Exact R0 version (66.5us known-good). 1563 blocks of 256 thr; ~12 KB LDS
// -> 8 blocks/CU; 4 outstanding 256B gathers per thread.
#define ACC8(e, mm) { float v = __int_as_float(e.y);                         \
    a[0] = fmaf(v, bflo(mm.x), a[0]); a[1] = fmaf(v, bfhi(mm.x), a[1]);      \
    a[2] = fmaf(v, bflo(mm.y), a[2]); a[3] = fmaf(v, bfhi(mm.y), a[3]);      \
    a[4] = fmaf(v, bflo(mm.z), a[4]); a[5] = fmaf(v, bfhi(mm.z), a[5]);      \
    a[6] = fmaf(v, bflo(mm.w), a[6]); a[7] = fmaf(v, bfhi(mm.w), a[7]); }

__global__ __launch_bounds__(256, 8) void bucket_gather(const unsigned short* __restrict__ support,
                                                        const int* __restrict__ gcursor,
                                                        const int2* __restrict__ epk,
                                                        float* __restrict__ out, int N) {
    __shared__ int2 se[CAPB];       // 11.3 KB
    __shared__ int  hist[BNODES];
    __shared__ int  rows[BNODES];
    __shared__ int  cur[BNODES];

    const int t   = threadIdx.x;
    const int b   = blockIdx.x;
    const int cnt = min(gcursor[b], CAPB);
    const int beg = b * CAPB;

    if (t < BNODES) hist[t] = 0;
    __syncthreads();

    // stage this thread's edges in registers: ONE global epk read total
    int2 r[RPT];
#pragma unroll
    for (int i = 0; i < RPT; ++i) {
        int idx = t + (i << 8);
        if (idx < cnt) r[i] = epk[beg + idx];
    }
#pragma unroll
    for (int i = 0; i < RPT; ++i) {
        int idx = t + (i << 8);
        if (idx < cnt) atomicAdd(&hist[(r[i].x >> 20) & (BNODES - 1)], 1);
    }
    __syncthreads();

    // Hillis-Steele inclusive scan of 64 counters
    if (t < BNODES) rows[t] = hist[t];
    __syncthreads();
#pragma unroll
    for (int off = 1; off < BNODES; off <<= 1) {
        int v = 0;
        if (t < BNODES && t >= off) v = rows[t - off];
        __syncthreads();
        if (t < BNODES && t >= off) rows[t] += v;
        __syncthreads();
    }
    if (t < BNODES) cur[t] = rows[t] - hist[t];
    __syncthreads();

    // scatter registers into sorted LDS order
#pragma unroll
    for (int i = 0; i < RPT; ++i) {
        int idx = t + (i << 8);
        if (idx < cnt) {
            int pos = atomicAdd(&cur[(r[i].x >> 20) & (BNODES - 1)], 1);
            se[pos] = r[i];
        }
    }
    __syncthreads();

    // per-node accumulation: group g (16 lanes) handles nodes g, g+16, ...
    const int g = t >> 4, lane = t & 15;
    const int node0 = b << NB_SHIFT;
    const uint4* S4 = (const uint4*)support;
    float4* o4 = (float4*)out;

#pragma unroll
    for (int nn = g; nn < BNODES; nn += 16) {
        const int send = rows[nn];
        const int sbeg = send - hist[nn];

        float a[8];
#pragma unroll
        for (int k = 0; k < 8; ++k) a[k] = 0.f;

        int j = sbeg;
        for (; j + 4 <= send; j += 4) {          // 4 outstanding 256 B gathers
            int2 e0 = se[j], e1 = se[j + 1], e2 = se[j + 2], e3 = se[j + 3];
            uint4 m0 = S4[(size_t)(e0.x & 0xFFFFF) * 16 + lane];
            uint4 m1 = S4[(size_t)(e1.x & 0xFFFFF) * 16 + lane];
            uint4 m2 = S4[(size_t)(e2.x & 0xFFFFF) * 16 + lane];
            uint4 m3 = S4[(size_t)(e3.x & 0xFFFFF) * 16 + lane];
            ACC8(e0, m0); ACC8(e1, m1); ACC8(e2, m2); ACC8(e3, m3);
        }
        for (; j < send; ++j) {
            int2 e0 = se[j];
            uint4 m0 = S4[(size_t)(e0.x & 0xFFFFF) * 16 + lane];
            ACC8(e0, m0);
        }

        const int gn = node0 + nn;
        if (gn < N) {
            size_t base = (size_t)gn * 32 + 2 * lane;
            float4 lo = make_float4(fmaxf(a[0], 0.f), fmaxf(a[1], 0.f),
                                    fmaxf(a[2], 0.f), fmaxf(a[3], 0.f));
            float4 hi = make_float4(fmaxf(a[4], 0.f), fmaxf(a[5], 0.f),
                                    fmaxf(a[6], 0.f), fmaxf(a[7], 0.f));
            o4[base]     = lo;
            o4[base + 1] = hi;
        }
    }
}

extern "C" void kernel_launch(void* const* d_in, const int* in_sizes, int n_in,
                              void* d_out, int out_size, void* d_ws, size_t ws_size,
                              hipStream_t stream) {
    const float* X    = (const float*)d_in[0];
    const float* W    = (const float*)d_in[1];
    const float* vals = (const float*)d_in[2];
    const int*   src  = (const int*)d_in[3];
    const int*   dst  = (const int*)d_in[4];
    float*       out  = (float*)d_out;

    const int N  = in_sizes[0] / D;
    const int E  = in_sizes[2];
    const int nb = (N + BNODES - 1) / BNODES;   // 1563

    size_t off = 0;
    auto take = [&](size_t bytes) {
        size_t p = off;
        off = (off + bytes + 255) & ~(size_t)255;
        return p;
    };
    char* ws = (char*)d_ws;
    size_t o_support = take((size_t)N * D * sizeof(unsigned short));
    size_t o_cursor  = take((size_t)nb * sizeof(int));
    size_t o_epk     = take(((size_t)nb * CAPB + 1024) * sizeof(int2));
    (void)ws_size;

    unsigned short* support = (unsigned short*)(ws + o_support);
    int*  cursor = (int*)(ws + o_cursor);
    int2* epk    = (int2*)(ws + o_epk);

    // 1) zero bucket cursors (stream-ordered, graph-capturable)
    hipMemsetAsync(cursor, 0, (size_t)nb * sizeof(int), stream);

    // 2) fused: fill2 (blocks 0..255) || gemm (blocks 256..256+nbG-1)
    //    gemm blocks transpose W fp32->bf16 in-LDS themselves (no wtrans).
    const int nbG = (N + 63) / 64;
    fused_pre<<<NFILL + nbG, 1024, 0, stream>>>(X, W, support, N,
                                                src, dst, vals, cursor, epk, E, nb);

    // 3) per-bucket sort + gather + ReLU
    bucket_gather<<<nb, 256, 0, stream>>>(support, cursor, epk, out, N);
}

// Round 4
// 197.237 us; speedup vs baseline: 1.1346x; 1.0822x over previous
//
#include <hip/hip_runtime.h>
#include <hip/hip_bf16.h>

// Pipeline (R11): wtrans -> fused(gemm||fill2) -> bucket_gather(column-split)
//  - R10 post-mortem: in-block W transpose cost ~10us across gemm blocks
//    (16-way LDS bank conflict on Wl[n4*XSTR+k] writes); wtrans kernel is
//    only ~3us. Reverted to R1's wtrans + WT-from-global gemm staging.
//  - R11 gather: COLUMN-SPLIT. Two blocks per bucket, block 2b+h gathers
//    cols h*64..h*64+63 (8 lanes x 16B = its own 128B cache line of each
//    support row). Grid 1563->3126 (6.1->12.2 blocks/CU): attacks the
//    measured 51% occupancy via TLP, after R8 showed ILP-deepening fails
//    on register recycling. Sort phase duplicated per half (block-parallel,
//    same wall time); epk read doubles (12.8->25.6MB, ~4us).

#define D 128
#define NB_SHIFT 6
#define BNODES 64
#define MAXB 2048            // >= nb = 1563
#define CAPB 1408            // mean 1023 + 12 sigma
#define RPT 6                // ceil(CAPB/256)
#define XSTR 136             // LDS row stride (ushorts): 272B = 4-bank shift/row
#define NFILL 256            // fill2 blocks in fused kernel (1 per CU)

using bf16x8 = __attribute__((ext_vector_type(8))) short;
using f32x4  = __attribute__((ext_vector_type(4))) float;

__device__ inline unsigned short f2bf(float f) {
    unsigned u = __float_as_uint(f);
    u += 0x7fffu + ((u >> 16) & 1u);
    return (unsigned short)(u >> 16);
}
__device__ inline float bflo(unsigned w) { return __uint_as_float(w << 16); }
__device__ inline float bfhi(unsigned w) { return __uint_as_float(w & 0xffff0000u); }

// ---------------- wtrans: WT[n][k] = bf16(W[k][n]); also zeroes cursor ----------------
__global__ __launch_bounds__(256) void wtrans(const float* __restrict__ W,
                                              unsigned short* __restrict__ WT,
                                              int* cursor, int nb) {
    const int t = threadIdx.x, b = blockIdx.x;   // 8 blocks
    const int n  = (b << 4) | (t & 15);
    const int k0 = (t >> 4) << 3;
#pragma unroll
    for (int k = k0; k < k0 + 8; ++k)
        WT[n * D + k] = f2bf(W[k * D + n]);
    if (b == 0)
        for (int i = t; i < nb; i += 256) cursor[i] = 0;
}

// ---------------- fused kernel: fill2 path + gemm path ----------------
// LDS union: gemm needs Xl(17.4KB)+Wl(34.8KB)=52.2KB; fill2 needs 16KB.
#define SMEM_BYTES (64 * XSTR * 2 + 128 * XSTR * 2)

__device__ void gemm_path(const float* __restrict__ X,
                          const unsigned short* __restrict__ WT,
                          unsigned short* __restrict__ S,
                          int nRows, int blk, char* smem) {
    unsigned short* Xl = (unsigned short*)smem;                    // [64][XSTR]
    unsigned short* Wl = (unsigned short*)(smem + 64 * XSTR * 2);  // [128][XSTR]

    const int t = threadIdx.x;                 // 0..1023
    const int row0 = blk * 64;

    // stage WT (16384 ushort = 2048 uint4), coalesced, 2 iters
    const uint4* WT4 = (const uint4*)WT;
    uint4* Wl4 = (uint4*)Wl;
#pragma unroll
    for (int i = t; i < 2048; i += 1024) {
        int n = i >> 4, kc8 = i & 15;
        Wl4[n * (XSTR / 8) + kc8] = WT4[i];
    }

    // stage X tile fp32 -> bf16 (2048 float4), 2 iters
    const float4* X4 = (const float4*)X;
    ushort4* Xl4 = (ushort4*)Xl;
#pragma unroll
    for (int i = t; i < 2048; i += 1024) {
        int r = i >> 5, c = i & 31;
        int gr = row0 + r;
        float4 v = make_float4(0.f, 0.f, 0.f, 0.f);
        if (gr < nRows) v = X4[(size_t)gr * 32 + c];
        ushort4 p;
        p.x = f2bf(v.x); p.y = f2bf(v.y); p.z = f2bf(v.z); p.w = f2bf(v.w);
        Xl4[r * (XSTR / 4) + c] = p;
    }
    __syncthreads();

    // 16 waves: wave w -> rows (w&3)*16..+15, nt pair (w>>2)*2..+1
    const int wv = t >> 6, lane = t & 63;
    const int m = lane & 15, quad = lane >> 4;
    const int m0  = (wv & 3) << 4;
    const int nt0 = (wv >> 2) << 1;

    f32x4 acc0 = {0.f, 0.f, 0.f, 0.f};
    f32x4 acc1 = {0.f, 0.f, 0.f, 0.f};

#pragma unroll
    for (int kc = 0; kc < 4; ++kc) {
        bf16x8 a = *(const bf16x8*)(Xl + (m0 + m) * XSTR + kc * 32 + quad * 8);
        bf16x8 b0 = *(const bf16x8*)(Wl + ((nt0 + 0) * 16 + m) * XSTR + kc * 32 + quad * 8);
        bf16x8 b1 = *(const bf16x8*)(Wl + ((nt0 + 1) * 16 + m) * XSTR + kc * 32 + quad * 8);
        acc0 = __builtin_amdgcn_mfma_f32_16x16x32_bf16(a, b0, acc0, 0, 0, 0);
        acc1 = __builtin_amdgcn_mfma_f32_16x16x32_bf16(a, b1, acc1, 0, 0, 0);
    }

    // D[row = quad*4+r][col = nt*16+m]
#pragma unroll
    for (int r = 0; r < 4; ++r) {
        int gr = row0 + m0 + quad * 4 + r;
        if (gr < nRows) {
            S[(size_t)gr * D + (nt0 + 0) * 16 + m] = f2bf(acc0[r]);
            S[(size_t)gr * D + (nt0 + 1) * 16 + m] = f2bf(acc1[r]);
        }
    }
}

__device__ void fill2_path(const int* __restrict__ src,
                           const int* __restrict__ dst,
                           const float* __restrict__ vals,
                           int* gcursor, int2* __restrict__ epk,
                           int E, int nb, int blk, char* smem) {
    int* h   = (int*)smem;                  // [MAXB]
    int* cur = (int*)(smem + MAXB * 4);     // [MAXB]
    const int t = threadIdx.x;              // 0..1023
    for (int i = t; i < nb; i += 1024) h[i] = 0;
    __syncthreads();

    int chunk = (E + NFILL - 1) / NFILL;
    chunk = (chunk + 3) & ~3;                     // keep int4 alignment
    const int s0 = min(E, blk * chunk);
    const int s1 = min(E, s0 + chunk);
    const int vend = s0 + ((s1 - s0) & ~3);       // int4 region

    // pass 1: histogram, int4 loads (4 edges/thread/iter)
    int e = s0 + (t << 2);
    for (; e + 4 <= vend; e += 4096) {
        int4 d = *(const int4*)(dst + e);
        atomicAdd(&h[d.x >> NB_SHIFT], 1);
        atomicAdd(&h[d.y >> NB_SHIFT], 1);
        atomicAdd(&h[d.z >> NB_SHIFT], 1);
        atomicAdd(&h[d.w >> NB_SHIFT], 1);
    }
    for (e = vend + t; e < s1; e += 1024) atomicAdd(&h[dst[e] >> NB_SHIFT], 1);
    __syncthreads();

    // reserve per-WG sub-window inside each bucket's fixed window
    for (int i = t; i < nb; i += 1024) {
        int c = h[i];
        cur[i] = c ? (i * CAPB + atomicAdd(&gcursor[i], c)) : 0;
    }
    __syncthreads();

    // pass 2: scatter
    e = s0 + (t << 2);
    for (; e + 4 <= vend; e += 4096) {
        int4   d = *(const int4*)(dst + e);
        int4   s = *(const int4*)(src + e);
        float4 v = *(const float4*)(vals + e);
        int p0 = atomicAdd(&cur[d.x >> NB_SHIFT], 1);
        int p1 = atomicAdd(&cur[d.y >> NB_SHIFT], 1);
        int p2 = atomicAdd(&cur[d.z >> NB_SHIFT], 1);
        int p3 = atomicAdd(&cur[d.w >> NB_SHIFT], 1);
        epk[p0] = make_int2(s.x | ((d.x & (BNODES - 1)) << 20), __float_as_int(v.x));
        epk[p1] = make_int2(s.y | ((d.y & (BNODES - 1)) << 20), __float_as_int(v.y));
        epk[p2] = make_int2(s.z | ((d.z & (BNODES - 1)) << 20), __float_as_int(v.z));
        epk[p3] = make_int2(s.w | ((d.w & (BNODES - 1)) << 20), __float_as_int(v.w));
    }
    for (e = vend + t; e < s1; e += 1024) {
        int d = dst[e];
        int pos = atomicAdd(&cur[d >> NB_SHIFT], 1);
        epk[pos] = make_int2(src[e] | ((d & (BNODES - 1)) << 20), __float_as_int(vals[e]));
    }
}

__global__ __launch_bounds__(1024, 8) void fused_pre(const float* __restrict__ X,
                                                     const unsigned short* __restrict__ WT,
                                                     unsigned short* __restrict__ S,
                                                     int nRows,
                                                     const int* __restrict__ src,
                                                     const int* __restrict__ dst,
                                                     const float* __restrict__ vals,
                                                     int* gcursor, int2* __restrict__ epk,
                                                     int E, int nb) {
    __shared__ char smem[SMEM_BYTES];
    const int bid = blockIdx.x;
    if (bid < NFILL)
        fill2_path(src, dst, vals, gcursor, epk, E, nb, bid, smem);
    else
        gemm_path(X, WT, S, nRows, bid - NFILL, smem);
}

// ---------------- bucket_gather: column-split, 2 blocks per bucket ----------------
// Block 2b+h: bucket b, output cols h*64..h*64+63. 3126 blocks of 256 thr;
// 12.3 KB LDS -> 8 blocks/CU; per-node group = 8 lanes x 16B (one 128B line).
#define ACC8(e, mm) { float v = __int_as_float(e.y);                         \
    a[0] = fmaf(v, bflo(mm.x), a[0]); a[1] = fmaf(v, bfhi(mm.x), a[1]);      \
    a[2] = fmaf(v, bflo(mm.y), a[2]); a[3] = fmaf(v, bfhi(mm.y), a[3]);      \
    a[4] = fmaf(v, bflo(mm.z), a[4]); a[5] = fmaf(v, bfhi(mm.z), a[5]);      \
    a[6] = fmaf(v, bflo(mm.w), a[6]); a[7] = fmaf(v, bfhi(mm.w), a[7]); }

__global__ __launch_bounds__(256, 8) void bucket_gather(const unsigned short* __restrict__ support,
                                                        const int* __restrict__ gcursor,
                                                        const int2* __restrict__ epk,
                                                        float* __restrict__ out, int N) {
    __shared__ int2 se[CAPB];       // 11.3 KB
    __shared__ int  hist[BNODES];
    __shared__ int  rows[BNODES];
    __shared__ int  cur[BNODES];

    const int t    = threadIdx.x;
    const int b    = blockIdx.x >> 1;     // bucket
    const int half = blockIdx.x & 1;      // column half (0: cols 0-63, 1: 64-127)
    const int cnt  = min(gcursor[b], CAPB);
    const int beg  = b * CAPB;

    if (t < BNODES) hist[t] = 0;
    __syncthreads();

    // stage this thread's edges in registers: ONE global epk read total
    int2 r[RPT];
#pragma unroll
    for (int i = 0; i < RPT; ++i) {
        int idx = t + (i << 8);
        if (idx < cnt) r[i] = epk[beg + idx];
    }
#pragma unroll
    for (int i = 0; i < RPT; ++i) {
        int idx = t + (i << 8);
        if (idx < cnt) atomicAdd(&hist[(r[i].x >> 20) & (BNODES - 1)], 1);
    }
    __syncthreads();

    // Hillis-Steele inclusive scan of 64 counters
    if (t < BNODES) rows[t] = hist[t];
    __syncthreads();
#pragma unroll
    for (int off = 1; off < BNODES; off <<= 1) {
        int v = 0;
        if (t < BNODES && t >= off) v = rows[t - off];
        __syncthreads();
        if (t < BNODES && t >= off) rows[t] += v;
        __syncthreads();
    }
    if (t < BNODES) cur[t] = rows[t] - hist[t];
    __syncthreads();

    // scatter registers into sorted LDS order
#pragma unroll
    for (int i = 0; i < RPT; ++i) {
        int idx = t + (i << 8);
        if (idx < cnt) {
            int pos = atomicAdd(&cur[(r[i].x >> 20) & (BNODES - 1)], 1);
            se[pos] = r[i];
        }
    }
    __syncthreads();

    // per-node accumulation: group g (8 lanes) handles nodes g, g+32
    const int g = t >> 3, lane = t & 7;
    const int node0 = b << NB_SHIFT;
    const int colbase = half << 3;               // uint4 offset within support row
    const uint4* S4 = (const uint4*)support;
    float4* o4 = (float4*)out;

#pragma unroll
    for (int nn = g; nn < BNODES; nn += 32) {
        const int send = rows[nn];
        const int sbeg = send - hist[nn];

        float a[8];
#pragma unroll
        for (int k = 0; k < 8; ++k) a[k] = 0.f;

        int j = sbeg;
        for (; j + 4 <= send; j += 4) {          // 4 outstanding 128 B gathers
            int2 e0 = se[j], e1 = se[j + 1], e2 = se[j + 2], e3 = se[j + 3];
            uint4 m0 = S4[(size_t)(e0.x & 0xFFFFF) * 16 + colbase + lane];
            uint4 m1 = S4[(size_t)(e1.x & 0xFFFFF) * 16 + colbase + lane];
            uint4 m2 = S4[(size_t)(e2.x & 0xFFFFF) * 16 + colbase + lane];
            uint4 m3 = S4[(size_t)(e3.x & 0xFFFFF) * 16 + colbase + lane];
            ACC8(e0, m0); ACC8(e1, m1); ACC8(e2, m2); ACC8(e3, m3);
        }
        for (; j < send; ++j) {
            int2 e0 = se[j];
            uint4 m0 = S4[(size_t)(e0.x & 0xFFFFF) * 16 + colbase + lane];
            ACC8(e0, m0);
        }

        const int gn = node0 + nn;
        if (gn < N) {
            size_t base = (size_t)gn * 32 + (half << 4) + 2 * lane;
            float4 lo = make_float4(fmaxf(a[0], 0.f), fmaxf(a[1], 0.f),
                                    fmaxf(a[2], 0.f), fmaxf(a[3], 0.f));
            float4 hi = make_float4(fmaxf(a[4], 0.f), fmaxf(a[5], 0.f),
                                    fmaxf(a[6], 0.f), fmaxf(a[7], 0.f));
            o4[base]     = lo;
            o4[base + 1] = hi;
        }
    }
}

extern "C" void kernel_launch(void* const* d_in, const int* in_sizes, int n_in,
                              void* d_out, int out_size, void* d_ws, size_t ws_size,
                              hipStream_t stream) {
    const float* X    = (const float*)d_in[0];
    const float* W    = (const float*)d_in[1];
    const float* vals = (const float*)d_in[2];
    const int*   src  = (const int*)d_in[3];
    const int*   dst  = (const int*)d_in[4];
    float*       out  = (float*)d_out;

    const int N  = in_sizes[0] / D;
    const int E  = in_sizes[2];
    const int nb = (N + BNODES - 1) / BNODES;   // 1563

    size_t off = 0;
    auto take = [&](size_t bytes) {
        size_t p = off;
        off = (off + bytes + 255) & ~(size_t)255;
        return p;
    };
    char* ws = (char*)d_ws;
    size_t o_support = take((size_t)N * D * sizeof(unsigned short));
    size_t o_wt      = take((size_t)D * D * sizeof(unsigned short));
    size_t o_cursor  = take((size_t)nb * sizeof(int));
    size_t o_epk     = take(((size_t)nb * CAPB + 1024) * sizeof(int2));
    (void)ws_size;

    unsigned short* support = (unsigned short*)(ws + o_support);
    unsigned short* WT      = (unsigned short*)(ws + o_wt);
    int*  cursor = (int*)(ws + o_cursor);
    int2* epk    = (int2*)(ws + o_epk);

    // 1) WT = bf16(W^T); zero bucket cursors
    wtrans<<<8, 256, 0, stream>>>(W, WT, cursor, nb);

    // 2) fused: fill2 (blocks 0..255) || gemm (blocks 256..256+nbG-1)
    const int nbG = (N + 63) / 64;
    fused_pre<<<NFILL + nbG, 1024, 0, stream>>>(X, WT, support, N,
                                                src, dst, vals, cursor, epk, E, nb);

    // 3) per-bucket sort + gather + ReLU (2 blocks per bucket, column-split)
    bucket_gather<<<2 * nb, 256, 0, stream>>>(support, cursor, epk, out, N);
}